// Round 2
// baseline (601.958 us; speedup 1.0000x reference)
//
#include <hip/hip_runtime.h>
#include <hip/hip_bf16.h>

#define Bc 4
#define Tc 2048
#define Dc 1024
#define Ec 4
#define WRc 128
#define Hc 4096
#define Mc (Bc*Tc)        // 8192
#define K1c (Dc+WRc)      // 1152
#define Pc (1+Ec)         // 5
#define ZDc (Pc*Dc)       // 5120
#define EPSc 1e-5f

typedef __attribute__((ext_vector_type(8))) short short8;
typedef __attribute__((ext_vector_type(4))) short short4v;
typedef __attribute__((ext_vector_type(4))) float f32x4;

__device__ __forceinline__ float wave_red_sum(float v) {
    #pragma unroll
    for (int o = 32; o > 0; o >>= 1) v += __shfl_down(v, o);
    return v;
}

__device__ __forceinline__ float gelu_tanh(float x) {
    const float c = 0.7978845608028654f;  // sqrt(2/pi)
    float x3 = x * x * x;
    return 0.5f * x * (1.0f + tanhf(c * (x + 0.044715f * x3)));
}

__device__ __forceinline__ void store_bf16x4(__hip_bfloat16* p, f32x4 v) {
    __hip_bfloat16 t[4];
    t[0] = __float2bfloat16(v[0]); t[1] = __float2bfloat16(v[1]);
    t[2] = __float2bfloat16(v[2]); t[3] = __float2bfloat16(v[3]);
    *(short4v*)p = *(const short4v*)t;
}

// ---------------- transpose + cast f32 [R][C] -> bf16 [C][R] ----------------
__global__ __launch_bounds__(256) void transpose_cast_kernel(
    const float* __restrict__ src, __hip_bfloat16* __restrict__ dst, int R, int C) {
    __shared__ float tile[32][33];
    int c0 = blockIdx.x * 32, r0 = blockIdx.y * 32;
    int tx = threadIdx.x, ty = threadIdx.y;
    #pragma unroll
    for (int i = ty; i < 32; i += 8)
        tile[i][tx] = src[(size_t)(r0 + i) * C + c0 + tx];
    __syncthreads();
    #pragma unroll
    for (int i = ty; i < 32; i += 8)
        dst[(size_t)(c0 + i) * R + r0 + tx] = __float2bfloat16(tile[tx][i]);
}

// ---------------- gate_w [5120][5] -> gwT [5][5120] -------------------------
__global__ __launch_bounds__(256) void gwT_kernel(
    const float* __restrict__ gw, float* __restrict__ gwT) {
    int i = blockIdx.x * 256 + threadIdx.x;   // < 5120
    #pragma unroll
    for (int j = 0; j < Pc; j++) gwT[j * ZDc + i] = gw[i * Pc + j];
}

// ------------- fused concat(x, r_feat) + LayerNorm -> bf16 [M][1152] --------
__global__ __launch_bounds__(256) void fuse_ln_kernel(
    const float* __restrict__ x, const float* __restrict__ rf,
    const float* __restrict__ g, const float* __restrict__ b,
    __hip_bfloat16* __restrict__ aln) {
    int row = blockIdx.x;
    int tid = threadIdx.x, lane = tid & 63, wave = tid >> 6;
    const f32x4* x4 = (const f32x4*)(x + (size_t)row * Dc);
    const f32x4* r4 = (const f32x4*)(rf + (size_t)row * WRc);

    f32x4 v0 = x4[tid];                       // floats 0..1023
    f32x4 v1 = {0.f, 0.f, 0.f, 0.f};          // floats 1024..1151 (tid<32)
    if (tid < 32) v1 = r4[tid];

    float s  = v0[0]+v0[1]+v0[2]+v0[3] + v1[0]+v1[1]+v1[2]+v1[3];
    float s2 = v0[0]*v0[0]+v0[1]*v0[1]+v0[2]*v0[2]+v0[3]*v0[3]
             + v1[0]*v1[0]+v1[1]*v1[1]+v1[2]*v1[2]+v1[3]*v1[3];

    __shared__ float red[8];
    float sw = wave_red_sum(s), s2w = wave_red_sum(s2);
    if (lane == 0) { red[wave] = sw; red[4 + wave] = s2w; }
    __syncthreads();
    float stot  = red[0] + red[1] + red[2] + red[3];
    float s2tot = red[4] + red[5] + red[6] + red[7];
    const float inv = 1.0f / (float)K1c;
    float mu = stot * inv;
    float var = s2tot * inv - mu * mu;
    float rstd = rsqrtf(var + EPSc);

    __hip_bfloat16* orow = aln + (size_t)row * K1c;
    {
        f32x4 gg = *(const f32x4*)(g + tid * 4);
        f32x4 bb = *(const f32x4*)(b + tid * 4);
        f32x4 o  = (v0 - mu) * rstd * gg + bb;
        store_bf16x4(orow + tid * 4, o);
    }
    if (tid < 32) {
        f32x4 gg = *(const f32x4*)(g + 1024 + tid * 4);
        f32x4 bb = *(const f32x4*)(b + 1024 + tid * 4);
        f32x4 o  = (v1 - mu) * rstd * gg + bb;
        store_bf16x4(orow + 1024 + tid * 4, o);
    }
}

// ------------- bf16 MFMA GEMM, BM=128 x BN, BK=64, compile-time dims --------
// A [M][K] bf16, Bt [N][K] bf16.
// EPI==0: out = bf16( gelu(acc + bias[col]) )
// EPI==1: out = f32 ( acc + bias[col] + add[row*N+col] )
template <int Mdim, int Ndim, int Kdim, int BN, int EPI>
__global__ __launch_bounds__(256) void gemm_kernel(
    const __hip_bfloat16* __restrict__ A, const __hip_bfloat16* __restrict__ Bt,
    const float* __restrict__ bias, const float* __restrict__ add,
    void* __restrict__ outp) {
    constexpr int BM = 128, BK = 64;
    constexpr int WN = BN / 2;            // per-wave N extent (2x2 wave grid)
    constexpr int MF = 4, NF = WN / 16;   // fragment repeats per wave
    constexpr int NTN = Ndim / BN;
    constexpr int NT  = (Mdim / BM) * NTN;
    constexpr int GB  = BN * 8 / 256;     // B-granules per thread (4 or 2)

    __shared__ __hip_bfloat16 As[BM * BK];
    __shared__ __hip_bfloat16 Bs[BN * BK];

    const int tid  = threadIdx.x;
    const int lane = tid & 63;
    const int wave = tid >> 6;
    const int wr = wave >> 1, wc = wave & 1;

    // XCD-aware bijective swizzle (NT % 8 == 0 for all instantiations here)
    constexpr int CPX = NT / 8;
    int bid = blockIdx.x;
    int swz = (bid & 7) * CPX + (bid >> 3);
    const int m0 = (swz / NTN) * BM;
    const int n0 = (swz % NTN) * BN;

    // per-thread staging source pointers (16B granules, 8/row at BK=64)
    const __hip_bfloat16* ag = A  + (size_t)(m0 + (tid >> 3)) * Kdim + (tid & 7) * 8;
    const __hip_bfloat16* bg = Bt + (size_t)(n0 + (tid >> 3)) * Kdim + (tid & 7) * 8;

    f32x4 acc[MF][NF] = {};

    for (int k0 = 0; k0 < Kdim; k0 += BK) {
        __syncthreads();   // previous iter's LDS reads complete
        #pragma unroll
        for (int i = 0; i < 4; i++)
            __builtin_amdgcn_global_load_lds(
                (const __attribute__((address_space(1))) void*)(ag + (size_t)i * 32 * Kdim),
                (__attribute__((address_space(3))) void*)(As + (i * 256 + tid) * 8), 16, 0, 0);
        #pragma unroll
        for (int i = 0; i < GB; i++)
            __builtin_amdgcn_global_load_lds(
                (const __attribute__((address_space(1))) void*)(bg + (size_t)i * 32 * Kdim),
                (__attribute__((address_space(3))) void*)(Bs + (i * 256 + tid) * 8), 16, 0, 0);
        ag += BK; bg += BK;
        __syncthreads();   // loads drained (vmcnt(0) before barrier)

        #pragma unroll
        for (int kk = 0; kk < 2; kk++) {
            short8 af[MF], bf[NF];
            #pragma unroll
            for (int m = 0; m < MF; m++)
                af[m] = *(const short8*)(As + (wr * 64 + m * 16 + (lane & 15)) * BK + kk * 32 + (lane >> 4) * 8);
            #pragma unroll
            for (int n = 0; n < NF; n++)
                bf[n] = *(const short8*)(Bs + (wc * WN + n * 16 + (lane & 15)) * BK + kk * 32 + (lane >> 4) * 8);
            #pragma unroll
            for (int m = 0; m < MF; m++)
                #pragma unroll
                for (int n = 0; n < NF; n++)
                    acc[m][n] = __builtin_amdgcn_mfma_f32_16x16x32_bf16(af[m], bf[n], acc[m][n], 0, 0, 0);
        }
    }

    // epilogue: C/D layout col = lane&15, row = (lane>>4)*4 + i
    #pragma unroll
    for (int m = 0; m < MF; m++) {
        int grow_base = m0 + wr * 64 + m * 16 + (lane >> 4) * 4;
        #pragma unroll
        for (int n = 0; n < NF; n++) {
            int gcol = n0 + wc * WN + n * 16 + (lane & 15);
            float bv = bias[gcol];
            #pragma unroll
            for (int i = 0; i < 4; i++) {
                int grow = grow_base + i;
                float vv = acc[m][n][i] + bv;
                if (EPI == 0) {
                    ((__hip_bfloat16*)outp)[(size_t)grow * Ndim + gcol] = __float2bfloat16(gelu_tanh(vv));
                } else {
                    ((float*)outp)[(size_t)grow * Ndim + gcol] = vv + add[(size_t)grow * Ndim + gcol];
                }
            }
        }
    }
}

// --------- fused path gating: LN(5120) -> 5 logits -> softmax -> mix --------
__global__ __launch_bounds__(256) void gate_kernel(
    const float* __restrict__ vtn, const float* __restrict__ dts,
    const float* __restrict__ g, const float* __restrict__ b,
    const float* __restrict__ gwT, const float* __restrict__ gb,
    float* __restrict__ out, float* __restrict__ gmem) {
    int row = blockIdx.x;                       // b*T + t
    int tid = threadIdx.x, lane = tid & 63, wave = tid >> 6;
    __shared__ f32x4 z4[ZDc / 4];               // 1280 vec4 = 20 KB
    __shared__ float red[8];
    __shared__ float lsum[Pc];
    if (tid < Pc) lsum[tid] = 0.f;

    const f32x4* vt4 = (const f32x4*)(vtn + (size_t)row * Dc);
    float s = 0.f, s2 = 0.f;
    #pragma unroll
    for (int k = 0; k < 5; k++) {
        int i4 = tid + k * 256;                 // 0..1279
        int p  = i4 >> 8;                       // path 0..4
        int d4 = i4 & 255;
        f32x4 u = (p == 0) ? vt4[d4]
                : *(const f32x4*)(dts + ((size_t)(p - 1) * Mc + row) * Dc + d4 * 4);
        z4[i4] = u;
        s  += u[0] + u[1] + u[2] + u[3];
        s2 += u[0]*u[0] + u[1]*u[1] + u[2]*u[2] + u[3]*u[3];
    }
    float sw = wave_red_sum(s), s2w = wave_red_sum(s2);
    if (lane == 0) { red[wave] = sw; red[4 + wave] = s2w; }
    __syncthreads();
    float stot  = red[0] + red[1] + red[2] + red[3];
    float s2tot = red[4] + red[5] + red[6] + red[7];
    const float inv = 1.0f / (float)ZDc;
    float mu = stot * inv;
    float var = s2tot * inv - mu * mu;
    float rstd = rsqrtf(var + EPSc);

    // 5-logit GEMV over normalized z (gwT is [5][5120] for coalesced loads)
    float lacc[Pc] = {0.f, 0.f, 0.f, 0.f, 0.f};
    #pragma unroll
    for (int k = 0; k < 5; k++) {
        int i4 = tid + k * 256;
        f32x4 zz = z4[i4];
        f32x4 gg = *(const f32x4*)(g + i4 * 4);
        f32x4 bb = *(const f32x4*)(b + i4 * 4);
        f32x4 zh = (zz - mu) * rstd * gg + bb;
        #pragma unroll
        for (int j = 0; j < Pc; j++) {
            f32x4 w = *(const f32x4*)(gwT + j * ZDc + i4 * 4);
            lacc[j] += zh[0]*w[0] + zh[1]*w[1] + zh[2]*w[2] + zh[3]*w[3];
        }
    }
    #pragma unroll
    for (int j = 0; j < Pc; j++) {
        float v = wave_red_sum(lacc[j]);
        if (lane == 0) atomicAdd(&lsum[j], v);
    }
    __syncthreads();

    float lg[Pc];
    #pragma unroll
    for (int j = 0; j < Pc; j++) lg[j] = lsum[j] + gb[j];
    float mx = lg[0];
    #pragma unroll
    for (int j = 1; j < Pc; j++) mx = fmaxf(mx, lg[j]);
    float ex[Pc], den = 0.f;
    #pragma unroll
    for (int j = 0; j < Pc; j++) { ex[j] = expf(lg[j] - mx); den += ex[j]; }
    float rden = 1.0f / den;
    float pi[Pc];
    #pragma unroll
    for (int j = 0; j < Pc; j++) pi[j] = ex[j] * rden;

    // out[d] = sum_p pi[p] * z[p][d]   (one float4 per thread: Dc/4 == 256)
    f32x4 o = {0.f, 0.f, 0.f, 0.f};
    #pragma unroll
    for (int p = 0; p < Pc; p++) o += pi[p] * z4[p * 256 + tid];
    *(f32x4*)(out + (size_t)row * Dc + tid * 4) = o;
    if (tid == 0) gmem[row] = pi[1] + pi[2] + pi[3] + pi[4];
}

extern "C" void kernel_launch(void* const* d_in, const int* in_sizes, int n_in,
                              void* d_out, int out_size, void* d_ws, size_t ws_size,
                              hipStream_t stream) {
    const float* x    = (const float*)d_in[0];
    const float* vt   = (const float*)d_in[1];
    const float* dts  = (const float*)d_in[2];
    const float* rf   = (const float*)d_in[3];
    const float* flg  = (const float*)d_in[4];
    const float* flb  = (const float*)d_in[5];
    const float* w1   = (const float*)d_in[6];
    const float* b1   = (const float*)d_in[7];
    const float* w2   = (const float*)d_in[8];
    const float* b2   = (const float*)d_in[9];
    const float* plg  = (const float*)d_in[10];
    const float* plb  = (const float*)d_in[11];
    const float* gw   = (const float*)d_in[12];
    const float* gb   = (const float*)d_in[13];

    char* ws = (char*)d_ws;
    size_t off = 0;
    __hip_bfloat16* w1t = (__hip_bfloat16*)(ws + off); off += (size_t)Hc * K1c * 2;   //  9.4 MB
    __hip_bfloat16* w2t = (__hip_bfloat16*)(ws + off); off += (size_t)Dc * Hc * 2;    //  8.4 MB
    __hip_bfloat16* aln = (__hip_bfloat16*)(ws + off); off += (size_t)Mc * K1c * 2;   // 18.9 MB
    __hip_bfloat16* h   = (__hip_bfloat16*)(ws + off); off += (size_t)Mc * Hc * 2;    // 67.1 MB
    float*          vtn = (float*)(ws + off);          off += (size_t)Mc * Dc * 4;    // 33.6 MB
    float*          gwT = (float*)(ws + off);          off += (size_t)Pc * ZDc * 4;   //  0.1 MB

    // weight prep
    transpose_cast_kernel<<<dim3(Hc / 32, K1c / 32), dim3(32, 8), 0, stream>>>(w1, w1t, K1c, Hc);
    transpose_cast_kernel<<<dim3(Dc / 32, Hc / 32), dim3(32, 8), 0, stream>>>(w2, w2t, Hc, Dc);
    gwT_kernel<<<ZDc / 256, 256, 0, stream>>>(gw, gwT);

    // fused concat + LN -> bf16 A
    fuse_ln_kernel<<<Mc, 256, 0, stream>>>(x, rf, flg, flb, aln);

    // h = gelu(A @ w1 + b1)  -> bf16 [M][H]   (2048 blocks)
    gemm_kernel<Mc, Hc, K1c, 128, 0><<<(Mc / 128) * (Hc / 128), 256, 0, stream>>>(
        aln, w1t, b1, nullptr, h);

    // vt_new = vt + h @ w2 + b2 -> f32 [M][D]  (128x64 tiles -> 1024 blocks)
    gemm_kernel<Mc, Dc, Hc, 64, 1><<<(Mc / 128) * (Dc / 64), 256, 0, stream>>>(
        h, w2t, b2, vt, vtn);

    // gating + mix -> out, g_mem
    float* outp = (float*)d_out;
    gate_kernel<<<Mc, 256, 0, stream>>>(vtn, dts, plg, plb, gwT, gb, outp, outp + (size_t)Mc * Dc);
}

// Round 4
// 550.541 us; speedup vs baseline: 1.0934x; 1.0934x over previous
//
#include <hip/hip_runtime.h>
#include <hip/hip_bf16.h>

#define Bc 4
#define Tc 2048
#define Dc 1024
#define Ec 4
#define WRc 128
#define Hc 4096
#define Mc (Bc*Tc)        // 8192
#define K1c (Dc+WRc)      // 1152
#define Pc (1+Ec)         // 5
#define ZDc (Pc*Dc)       // 5120
#define EPSc 1e-5f

typedef __attribute__((ext_vector_type(8))) short short8;
typedef __attribute__((ext_vector_type(4))) short short4v;
typedef __attribute__((ext_vector_type(4))) float f32x4;

__device__ __forceinline__ float wave_red_sum(float v) {
    #pragma unroll
    for (int o = 32; o > 0; o >>= 1) v += __shfl_down(v, o);
    return v;
}

__device__ __forceinline__ float gelu_tanh(float x) {
    const float c = 0.7978845608028654f;  // sqrt(2/pi)
    float x3 = x * x * x;
    return 0.5f * x * (1.0f + tanhf(c * (x + 0.044715f * x3)));
}

__device__ __forceinline__ void store_bf16x4(__hip_bfloat16* p, f32x4 v) {
    __hip_bfloat16 t[4];
    t[0] = __float2bfloat16(v[0]); t[1] = __float2bfloat16(v[1]);
    t[2] = __float2bfloat16(v[2]); t[3] = __float2bfloat16(v[3]);
    *(short4v*)p = *(const short4v*)t;
}

// ---------------- transpose + cast f32 [R][C] -> bf16 [C][R] ----------------
__global__ __launch_bounds__(256) void transpose_cast_kernel(
    const float* __restrict__ src, __hip_bfloat16* __restrict__ dst, int R, int C) {
    __shared__ float tile[32][33];
    int c0 = blockIdx.x * 32, r0 = blockIdx.y * 32;
    int tx = threadIdx.x, ty = threadIdx.y;
    #pragma unroll
    for (int i = ty; i < 32; i += 8)
        tile[i][tx] = src[(size_t)(r0 + i) * C + c0 + tx];
    __syncthreads();
    #pragma unroll
    for (int i = ty; i < 32; i += 8)
        dst[(size_t)(c0 + i) * R + r0 + tx] = __float2bfloat16(tile[tx][i]);
}

// ---------------- gate_w [5120][5] -> gwT [5][5120] -------------------------
__global__ __launch_bounds__(256) void gwT_kernel(
    const float* __restrict__ gw, float* __restrict__ gwT) {
    int i = blockIdx.x * 256 + threadIdx.x;   // < 5120
    #pragma unroll
    for (int j = 0; j < Pc; j++) gwT[j * ZDc + i] = gw[i * Pc + j];
}

// ------------- fused concat(x, r_feat) + LayerNorm -> bf16 [M][1152] --------
__global__ __launch_bounds__(256) void fuse_ln_kernel(
    const float* __restrict__ x, const float* __restrict__ rf,
    const float* __restrict__ g, const float* __restrict__ b,
    __hip_bfloat16* __restrict__ aln) {
    int row = blockIdx.x;
    int tid = threadIdx.x, lane = tid & 63, wave = tid >> 6;
    const f32x4* x4 = (const f32x4*)(x + (size_t)row * Dc);
    const f32x4* r4 = (const f32x4*)(rf + (size_t)row * WRc);

    f32x4 v0 = x4[tid];                       // floats 0..1023
    f32x4 v1 = {0.f, 0.f, 0.f, 0.f};          // floats 1024..1151 (tid<32)
    if (tid < 32) v1 = r4[tid];

    float s  = v0[0]+v0[1]+v0[2]+v0[3] + v1[0]+v1[1]+v1[2]+v1[3];
    float s2 = v0[0]*v0[0]+v0[1]*v0[1]+v0[2]*v0[2]+v0[3]*v0[3]
             + v1[0]*v1[0]+v1[1]*v1[1]+v1[2]*v1[2]+v1[3]*v1[3];

    __shared__ float red[8];
    float sw = wave_red_sum(s), s2w = wave_red_sum(s2);
    if (lane == 0) { red[wave] = sw; red[4 + wave] = s2w; }
    __syncthreads();
    float stot  = red[0] + red[1] + red[2] + red[3];
    float s2tot = red[4] + red[5] + red[6] + red[7];
    const float inv = 1.0f / (float)K1c;
    float mu = stot * inv;
    float var = s2tot * inv - mu * mu;
    float rstd = rsqrtf(var + EPSc);

    __hip_bfloat16* orow = aln + (size_t)row * K1c;
    {
        f32x4 gg = *(const f32x4*)(g + tid * 4);
        f32x4 bb = *(const f32x4*)(b + tid * 4);
        f32x4 o  = (v0 - mu) * rstd * gg + bb;
        store_bf16x4(orow + tid * 4, o);
    }
    if (tid < 32) {
        f32x4 gg = *(const f32x4*)(g + 1024 + tid * 4);
        f32x4 bb = *(const f32x4*)(b + 1024 + tid * 4);
        f32x4 o  = (v1 - mu) * rstd * gg + bb;
        store_bf16x4(orow + 1024 + tid * 4, o);
    }
}

// ===================== pipelined bf16 MFMA GEMM =============================
// BM=256, BN=128, BK=64, 512 threads (8 waves, 4x2), 3-deep LDS pipeline with
// counted vmcnt (never 0 in steady state), T2 XOR-swizzle:
// LDS[row][cg] = Global[row][cg ^ (row&7)] via pre-swizzled global source
// granule + linear global_load_lds dest; ds_read applies the same XOR.
// A [M][K] bf16, Bt [N][K] bf16.
// EPI==0: out = bf16( gelu(acc + bias[col]) )
// EPI==1: out = f32 ( acc + bias[col] + add[row*N+col] )
template <int Mdim, int Ndim, int Kdim, int EPI>
__global__ __launch_bounds__(512, 2) void gemm_pipe_kernel(
    const __hip_bfloat16* __restrict__ A, const __hip_bfloat16* __restrict__ Bt,
    const float* __restrict__ bias, const float* __restrict__ add,
    void* __restrict__ outp) {
    constexpr int BM = 256, BN = 128, BK = 64;
    constexpr int NTK = Kdim / BK;
    constexpr int NTN = Ndim / BN;
    constexpr int NT  = (Mdim / BM) * NTN;
    constexpr int ATILE = BM * BK;   // 16384 elems (32 KB)
    constexpr int BTILE = BN * BK;   //  8192 elems (16 KB)

    __shared__ __hip_bfloat16 As[3 * ATILE];   // 96 KB
    __shared__ __hip_bfloat16 Bs[3 * BTILE];   // 48 KB

    const int tid  = threadIdx.x;
    const int lane = tid & 63;
    const int wave = tid >> 6;
    const int wr = wave >> 1, wc = wave & 1;   // 4x2 wave grid

    // XCD-aware bijective swizzle (NT % 8 == 0 here)
    constexpr int CPX = NT / 8;
    int bid = blockIdx.x;
    int swz = (bid & 7) * CPX + (bid >> 3);
    const int m0 = (swz / NTN) * BM;
    const int n0 = (swz % NTN) * BN;

    // staging: thread t owns 16B granules; dest is LINEAR (granule i*512+tid),
    // source col-granule pre-swizzled: g' = (t&7) ^ (row&7)
    const int srow  = tid >> 3;                  // 0..63 (row within 64-row sweep)
    const int scolg = (tid & 7) ^ (srow & 7);
    const __hip_bfloat16* aSrc = A  + (size_t)(m0 + srow) * Kdim + scolg * 8;
    const __hip_bfloat16* bSrc = Bt + (size_t)(n0 + srow) * Kdim + scolg * 8;

    auto stage = [&](int t) {
        const __hip_bfloat16* ap = aSrc + (size_t)t * BK;
        const __hip_bfloat16* bp = bSrc + (size_t)t * BK;
        __hip_bfloat16* ad = As + (t % 3) * ATILE + tid * 8;
        __hip_bfloat16* bd = Bs + (t % 3) * BTILE + tid * 8;
        #pragma unroll
        for (int i = 0; i < 4; i++)            // A: 4 sweeps x 64 rows
            __builtin_amdgcn_global_load_lds(
                (const __attribute__((address_space(1))) void*)(ap + (size_t)i * 64 * Kdim),
                (__attribute__((address_space(3))) void*)(ad + i * 4096), 16, 0, 0);
        #pragma unroll
        for (int i = 0; i < 2; i++)            // B: 2 sweeps x 64 rows
            __builtin_amdgcn_global_load_lds(
                (const __attribute__((address_space(1))) void*)(bp + (size_t)i * 64 * Kdim),
                (__attribute__((address_space(3))) void*)(bd + i * 4096), 16, 0, 0);
    };

    f32x4 acc[4][4] = {};

    auto compute = [&](int t) {
        const __hip_bfloat16* Ab = As + (t % 3) * ATILE;
        const __hip_bfloat16* Bb = Bs + (t % 3) * BTILE;
        #pragma unroll
        for (int kk = 0; kk < 2; kk++) {
            short8 af[4], bf[4];
            #pragma unroll
            for (int m = 0; m < 4; m++) {
                int row = wr * 64 + m * 16 + (lane & 15);
                int col = (kk * 32 + (lane >> 4) * 8) ^ ((row & 7) << 3);  // elem-domain XOR
                af[m] = *(const short8*)(Ab + row * 64 + col);
            }
            #pragma unroll
            for (int n = 0; n < 4; n++) {
                int row = wc * 64 + n * 16 + (lane & 15);
                int col = (kk * 32 + (lane >> 4) * 8) ^ ((row & 7) << 3);
                bf[n] = *(const short8*)(Bb + row * 64 + col);
            }
            #pragma unroll
            for (int m = 0; m < 4; m++)
                #pragma unroll
                for (int n = 0; n < 4; n++)
                    acc[m][n] = __builtin_amdgcn_mfma_f32_16x16x32_bf16(af[m], bf[n], acc[m][n], 0, 0, 0);
        }
    };

    // prologue: 2 tiles in flight (6 loads each)
    stage(0);
    stage(1);
    // steady state: stage t+2; wait until only tiles t+1,t+2 outstanding (12)
    for (int t = 0; t < NTK - 2; ++t) {
        stage(t + 2);
        asm volatile("s_waitcnt vmcnt(12)" ::: "memory");
        __builtin_amdgcn_sched_barrier(0);
        __builtin_amdgcn_s_barrier();
        __builtin_amdgcn_sched_barrier(0);   // no ds_read hoisted above barrier
        compute(t);
        __builtin_amdgcn_sched_barrier(0);
        __builtin_amdgcn_s_barrier();
        __builtin_amdgcn_sched_barrier(0);   // no next-stage writes hoisted above
    }
    // tail: t = NTK-2 (1 tile still in flight), t = NTK-1 (none)
    asm volatile("s_waitcnt vmcnt(6)" ::: "memory");
    __builtin_amdgcn_sched_barrier(0);
    __builtin_amdgcn_s_barrier();
    __builtin_amdgcn_sched_barrier(0);
    compute(NTK - 2);
    __builtin_amdgcn_sched_barrier(0);
    __builtin_amdgcn_s_barrier();
    __builtin_amdgcn_sched_barrier(0);
    asm volatile("s_waitcnt vmcnt(0)" ::: "memory");
    __builtin_amdgcn_sched_barrier(0);
    compute(NTK - 1);

    // epilogue: C/D layout col = lane&15, row = (lane>>4)*4 + i
    #pragma unroll
    for (int m = 0; m < 4; m++) {
        int grow_base = m0 + wr * 64 + m * 16 + (lane >> 4) * 4;
        #pragma unroll
        for (int n = 0; n < 4; n++) {
            int gcol = n0 + wc * 64 + n * 16 + (lane & 15);
            float bv = bias[gcol];
            #pragma unroll
            for (int i = 0; i < 4; i++) {
                int grow = grow_base + i;
                float vv = acc[m][n][i] + bv;
                if (EPI == 0) {
                    ((__hip_bfloat16*)outp)[(size_t)grow * Ndim + gcol] = __float2bfloat16(gelu_tanh(vv));
                } else {
                    ((float*)outp)[(size_t)grow * Ndim + gcol] = vv + add[(size_t)grow * Ndim + gcol];
                }
            }
        }
    }
}

// --------- fused path gating: LN(5120) -> 5 logits -> softmax -> mix --------
// All path data held in registers (thread's chunk p == path p at its own
// d-group): no LDS z buffer needed.
__global__ __launch_bounds__(256) void gate_kernel(
    const float* __restrict__ vtn, const float* __restrict__ dts,
    const float* __restrict__ g, const float* __restrict__ b,
    const float* __restrict__ gwT, const float* __restrict__ gb,
    float* __restrict__ out, float* __restrict__ gmem) {
    int row = blockIdx.x;                       // b*T + t
    int tid = threadIdx.x, lane = tid & 63, wave = tid >> 6;
    __shared__ float red[8];
    __shared__ float lsum[Pc];
    if (tid < Pc) lsum[tid] = 0.f;

    // v[p] = paths[p][row][tid*4 .. tid*4+3]
    f32x4 v[Pc];
    v[0] = *(const f32x4*)(vtn + (size_t)row * Dc + tid * 4);
    #pragma unroll
    for (int p = 1; p < Pc; p++)
        v[p] = *(const f32x4*)(dts + ((size_t)(p - 1) * Mc + row) * Dc + tid * 4);

    float s = 0.f, s2 = 0.f;
    #pragma unroll
    for (int p = 0; p < Pc; p++) {
        s  += v[p][0] + v[p][1] + v[p][2] + v[p][3];
        s2 += v[p][0]*v[p][0] + v[p][1]*v[p][1] + v[p][2]*v[p][2] + v[p][3]*v[p][3];
    }
    float sw = wave_red_sum(s), s2w = wave_red_sum(s2);
    if (lane == 0) { red[wave] = sw; red[4 + wave] = s2w; }
    __syncthreads();
    float stot  = red[0] + red[1] + red[2] + red[3];
    float s2tot = red[4] + red[5] + red[6] + red[7];
    const float inv = 1.0f / (float)ZDc;
    float mu = stot * inv;
    float var = s2tot * inv - mu * mu;
    float rstd = rsqrtf(var + EPSc);

    // 5-logit GEMV over normalized z (z index i4 = p*256 + tid)
    float lacc[Pc] = {0.f, 0.f, 0.f, 0.f, 0.f};
    #pragma unroll
    for (int p = 0; p < Pc; p++) {
        int i4 = p * 256 + tid;
        f32x4 gg = *(const f32x4*)(g + i4 * 4);
        f32x4 bb = *(const f32x4*)(b + i4 * 4);
        f32x4 zh = (v[p] - mu) * rstd * gg + bb;
        #pragma unroll
        for (int j = 0; j < Pc; j++) {
            f32x4 w = *(const f32x4*)(gwT + j * ZDc + i4 * 4);
            lacc[j] += zh[0]*w[0] + zh[1]*w[1] + zh[2]*w[2] + zh[3]*w[3];
        }
    }
    #pragma unroll
    for (int j = 0; j < Pc; j++) {
        float vv = wave_red_sum(lacc[j]);
        if (lane == 0) atomicAdd(&lsum[j], vv);
    }
    __syncthreads();

    float lg[Pc];
    #pragma unroll
    for (int j = 0; j < Pc; j++) lg[j] = lsum[j] + gb[j];
    float mx = lg[0];
    #pragma unroll
    for (int j = 1; j < Pc; j++) mx = fmaxf(mx, lg[j]);
    float ex[Pc], den = 0.f;
    #pragma unroll
    for (int j = 0; j < Pc; j++) { ex[j] = expf(lg[j] - mx); den += ex[j]; }
    float rden = 1.0f / den;
    float pi[Pc];
    #pragma unroll
    for (int j = 0; j < Pc; j++) pi[j] = ex[j] * rden;

    f32x4 o = {0.f, 0.f, 0.f, 0.f};
    #pragma unroll
    for (int p = 0; p < Pc; p++) o += pi[p] * v[p];
    *(f32x4*)(out + (size_t)row * Dc + tid * 4) = o;
    if (tid == 0) gmem[row] = pi[1] + pi[2] + pi[3] + pi[4];
}

extern "C" void kernel_launch(void* const* d_in, const int* in_sizes, int n_in,
                              void* d_out, int out_size, void* d_ws, size_t ws_size,
                              hipStream_t stream) {
    const float* x    = (const float*)d_in[0];
    const float* vt   = (const float*)d_in[1];
    const float* dts  = (const float*)d_in[2];
    const float* rf   = (const float*)d_in[3];
    const float* flg  = (const float*)d_in[4];
    const float* flb  = (const float*)d_in[5];
    const float* w1   = (const float*)d_in[6];
    const float* b1   = (const float*)d_in[7];
    const float* w2   = (const float*)d_in[8];
    const float* b2   = (const float*)d_in[9];
    const float* plg  = (const float*)d_in[10];
    const float* plb  = (const float*)d_in[11];
    const float* gw   = (const float*)d_in[12];
    const float* gb   = (const float*)d_in[13];

    char* ws = (char*)d_ws;
    size_t off = 0;
    __hip_bfloat16* w1t = (__hip_bfloat16*)(ws + off); off += (size_t)Hc * K1c * 2;   //  9.4 MB
    __hip_bfloat16* w2t = (__hip_bfloat16*)(ws + off); off += (size_t)Dc * Hc * 2;    //  8.4 MB
    __hip_bfloat16* aln = (__hip_bfloat16*)(ws + off); off += (size_t)Mc * K1c * 2;   // 18.9 MB
    __hip_bfloat16* h   = (__hip_bfloat16*)(ws + off); off += (size_t)Mc * Hc * 2;    // 67.1 MB
    float*          vtn = (float*)(ws + off);          off += (size_t)Mc * Dc * 4;    // 33.6 MB
    float*          gwT = (float*)(ws + off);          off += (size_t)Pc * ZDc * 4;   //  0.1 MB

    // weight prep
    transpose_cast_kernel<<<dim3(Hc / 32, K1c / 32), dim3(32, 8), 0, stream>>>(w1, w1t, K1c, Hc);
    transpose_cast_kernel<<<dim3(Dc / 32, Hc / 32), dim3(32, 8), 0, stream>>>(w2, w2t, Hc, Dc);
    gwT_kernel<<<ZDc / 256, 256, 0, stream>>>(gw, gwT);

    // fused concat + LN -> bf16 A
    fuse_ln_kernel<<<Mc, 256, 0, stream>>>(x, rf, flg, flb, aln);

    // h = gelu(A @ w1 + b1) -> bf16 [M][H]   (32x32 = 1024 blocks)
    gemm_pipe_kernel<Mc, Hc, K1c, 0><<<(Mc / 256) * (Hc / 128), 512, 0, stream>>>(
        aln, w1t, b1, nullptr, h);

    // vt_new = vt + h @ w2 + b2 -> f32 [M][D]  (32x8 = 256 blocks)
    gemm_pipe_kernel<Mc, Dc, Hc, 1><<<(Mc / 256) * (Dc / 128), 512, 0, stream>>>(
        h, w2t, b2, vt, vtn);

    // gating + mix -> out, g_mem
    float* outp = (float*)d_out;
    gate_kernel<<<Mc, 256, 0, stream>>>(vtn, dts, plg, plb, gwT, gb, outp, outp + (size_t)Mc * Dc);
}